// Round 12
// baseline (328.049 us; speedup 1.0000x reference)
//
#include <hip/hip_runtime.h>
#include <hip/hip_bf16.h>
#include <stdint.h>

typedef __bf16 bf16x8 __attribute__((ext_vector_type(8)));
typedef float f32x16 __attribute__((ext_vector_type(16)));
typedef unsigned short ushort_t;
typedef ushort_t ushort8 __attribute__((ext_vector_type(8)));

#define GLDS16(g, l) __builtin_amdgcn_global_load_lds(                          \
    (const __attribute__((address_space(1))) void*)(g),                         \
    (__attribute__((address_space(3))) void*)(l), 16, 0, 0)

__device__ __constant__ float NF4_LUT_C[16] = {
    -1.0f, -0.6961928009986877f, -0.5250730514526367f, -0.39491748809814453f,
    -0.28444138169288635f, -0.18477343022823334f, -0.09105003625154495f, 0.0f,
    0.07958029955625534f, 0.16093020141124725f, 0.24611230194568634f,
    0.33791524171829224f, 0.44070982933044434f, 0.5626170039176941f,
    0.7229568362236023f, 1.0f};

__device__ inline ushort_t f32_to_bf16(float f) {
    uint32_t u = __builtin_bit_cast(uint32_t, f);
    u += 0x7FFFu + ((u >> 16) & 1u);
    return (ushort_t)(u >> 16);
}

// Packed fragment layout: chunk (b, kb) = 1KB; lane l, elems e 0..7 hold
// value[row = b*32 + (l&31)][k = kb*16 + (l>>5)*8 + e].
// Flat ushort index: (b*256 + kb)*512 + l*8 + e.

// ---------------------------------------------------------------------------
// Kernel 1: cast x (fp32) -> bf16 packed fragments (r9/r10-verified)
// ---------------------------------------------------------------------------
__global__ __launch_bounds__(256) void cast_x_kernel(
    const float* __restrict__ x, ushort_t* __restrict__ A_pk)
{
    __shared__ ushort_t lt[32][130];
    const int t  = threadIdx.x;
    const int mb = blockIdx.x >> 5;
    const int kc = blockIdx.x & 31;

    {
        const int rl = t >> 3;
        const int c0 = (t & 7) * 16;
        const float4* p = reinterpret_cast<const float4*>(
            x + (size_t)(mb * 32 + rl) * 4096 + kc * 128 + c0);
        #pragma unroll
        for (int q = 0; q < 4; ++q) {
            float4 a = p[q];
            lt[rl][c0 + q * 4 + 0] = f32_to_bf16(a.x);
            lt[rl][c0 + q * 4 + 1] = f32_to_bf16(a.y);
            lt[rl][c0 + q * 4 + 2] = f32_to_bf16(a.z);
            lt[rl][c0 + q * 4 + 3] = f32_to_bf16(a.w);
        }
    }
    __syncthreads();

    ushort_t* dst = A_pk + ((size_t)mb * 256 + kc * 8) * 512 + t * 16;
    #pragma unroll
    for (int h = 0; h < 2; ++h) {
        const int c  = 2 * t + h;
        const int kb = c >> 6;
        const int l  = c & 63;
        const int rl = l & 31;
        const int k0 = kb * 16 + (l >> 5) * 8;
        ushort8 v;
        #pragma unroll
        for (int e = 0; e < 8; ++e) v[e] = lt[rl][k0 + e];
        *reinterpret_cast<ushort8*>(dst + h * 8) = v;
    }
}

// ---------------------------------------------------------------------------
// Kernel 2: NF4 dequant -> packed B fragments (r9/r10-verified)
// ---------------------------------------------------------------------------
__global__ __launch_bounds__(256) void nf4_dequant_t_kernel(
    const int* __restrict__ q, const float* __restrict__ scales,
    ushort_t* __restrict__ B_pk)
{
    __shared__ float lut[16];
    __shared__ ushort_t tile[64][65];
    const int t = threadIdx.x;
    if (t < 16) lut[t] = NF4_LUT_C[t];
    __syncthreads();

    const int nt = blockIdx.x & 63;
    const int kt = blockIdx.x >> 6;

    #pragma unroll
    for (int L = t; L < 512; L += 256) {
        const int r  = L >> 3;
        const int qd = L & 7;
        const int k  = kt * 64 + r;
        const int4 e4 = *reinterpret_cast<const int4*>(q + (size_t)k * 2048 + nt * 32 + qd * 4);
        const float s = scales[k * 64 + nt];
        const int nb = qd * 8;
        int bts[4] = {e4.x, e4.y, e4.z, e4.w};
        #pragma unroll
        for (int e = 0; e < 4; ++e) {
            const int byte = bts[e];
            tile[r][nb + e * 2]     = f32_to_bf16(lut[(byte >> 4) & 0xF] * s);
            tile[r][nb + e * 2 + 1] = f32_to_bf16(lut[byte & 0xF] * s);
        }
    }
    __syncthreads();

    #pragma unroll
    for (int h = 0; h < 2; ++h) {
        const int c   = 2 * t + h;
        const int nbl = c >> 8;
        const int kbl = (c >> 6) & 3;
        const int l   = c & 63;
        const int nl  = nbl * 32 + (l & 31);
        const int k0  = kbl * 16 + (l >> 5) * 8;
        ushort8 v;
        #pragma unroll
        for (int e = 0; e < 8; ++e) v[e] = tile[k0 + e][nl];
        ushort_t* dst = B_pk + ((size_t)(nt * 2 + nbl) * 256 + kt * 4 + kbl) * 512 + l * 8;
        *reinterpret_cast<ushort8*>(dst) = v;
    }
}

// ---------------------------------------------------------------------------
// Kernel 3: bf16 GEMM, 256x256 tile, BK=32, 8 waves (2M x 4N), 32x32x16 MFMA.
// r10's proven packed-fragment body, ring shrunk 4->2 slots (64KB LDS) so
// TWO blocks co-reside per CU (VGPR=100 <= 128): inter-block TLP covers the
// depth-1 vmcnt(0) drain (m114). Stage tile t+1 at top of tile t into the
// dead slot (its reads fed t-1's MFMAs before the t-1 closing barrier).
// Grid 512 = 2 blocks/CU x 256 CUs, one co-resident dispatch round.
// ---------------------------------------------------------------------------
__global__ __launch_bounds__(512, 2) void gemm_nf4_kernel(
    const ushort_t* __restrict__ A_pk, const ushort_t* __restrict__ B_pk,
    const float* __restrict__ bias, float* __restrict__ C)
{
    // per slot: A 8mb x 2kb x 512 = 16KB + B 16KB; 2 slots = 64KB
    __shared__ __align__(16) ushort_t As[2][8192];
    __shared__ __align__(16) ushort_t Bs[2][8192];

    const int tid  = threadIdx.x;
    const int lane = tid & 63;
    const int w8   = tid >> 6;       // 0..7
    const int wr   = w8 >> 2;        // 0..1 -> 128-row A strip
    const int wc   = w8 & 3;         // 0..3 -> 64-col B strip
    const int ln31 = lane & 31;
    const int lq2  = lane >> 5;      // 0..1

    // XCD-aware bijective swizzle (512 % 8 == 0)
    const int wg  = blockIdx.x;
    const int swz = (wg & 7) * 64 + (wg >> 3);
    const int m0  = (swz >> 4) * 256;   // 32 m-tiles
    const int n0  = (swz & 15) * 256;   // 16 n-tiles

    // staging sources: wave w8 owns m-block (m0/32 + w8) of A / n-block of B;
    // per tile it stages kb 0,1 (1KB contiguous chunks, lane -> +lane*16B)
    const ushort_t* gA = A_pk + ((size_t)(m0 >> 5) + w8) * (256 * 512) + lane * 8;
    const ushort_t* gB = B_pk + ((size_t)(n0 >> 5) + w8) * (256 * 512) + lane * 8;

    f32x16 acc[4][2];
    #pragma unroll
    for (int i = 0; i < 4; ++i)
        #pragma unroll
        for (int j = 0; j < 2; ++j)
            acc[i][j] = (f32x16){0.f};

    // fragment LDS offsets: A frag (i,kk) at wr*4096 + i*1024 + kk*512 + lane*8
    const int aBase = wr * 4096 + lane * 8;
    const int bBase = wc * 2048 + lane * 8;

    // prologue: stage tile 0 -> slot 0 (4 loads/wave), drain, barrier
    #pragma unroll
    for (int kb = 0; kb < 2; ++kb) {
        GLDS16(gA + kb * 512, &As[0][(w8 * 2 + kb) * 512]);
        GLDS16(gB + kb * 512, &Bs[0][(w8 * 2 + kb) * 512]);
    }
    asm volatile("s_waitcnt vmcnt(0)" ::: "memory");
    __builtin_amdgcn_s_barrier();
    __builtin_amdgcn_sched_barrier(0);

    for (int t = 0; t < 128; ++t) {
        const int slot = t & 1;
        const ushort_t* Asl = &As[slot][aBase];
        const ushort_t* Bsl = &Bs[slot][bBase];
        const int kof = (t + 1) * 1024;

        // ---- kk = 0: frag reads + stage A chunks of tile t+1 + 8 MFMA ----
        bf16x8 af0[4], bf0[2], af1[4], bf1[2];
        #pragma unroll
        for (int i = 0; i < 4; ++i)
            af0[i] = *reinterpret_cast<const bf16x8*>(Asl + i * 1024);
        #pragma unroll
        for (int j = 0; j < 2; ++j)
            bf0[j] = *reinterpret_cast<const bf16x8*>(Bsl + j * 1024);
        if (t < 127) {
            GLDS16(gA + kof,       &As[slot ^ 1][(w8 * 2) * 512]);
            GLDS16(gA + kof + 512, &As[slot ^ 1][(w8 * 2 + 1) * 512]);
        }
        __builtin_amdgcn_s_setprio(1);
        #pragma unroll
        for (int i = 0; i < 4; ++i)
            #pragma unroll
            for (int j = 0; j < 2; ++j)
                acc[i][j] = __builtin_amdgcn_mfma_f32_32x32x16_bf16(
                    af0[i], bf0[j], acc[i][j], 0, 0, 0);
        __builtin_amdgcn_s_setprio(0);

        // ---- kk = 1: frag reads + stage B chunks of tile t+1 + 8 MFMA ----
        #pragma unroll
        for (int i = 0; i < 4; ++i)
            af1[i] = *reinterpret_cast<const bf16x8*>(Asl + i * 1024 + 512);
        #pragma unroll
        for (int j = 0; j < 2; ++j)
            bf1[j] = *reinterpret_cast<const bf16x8*>(Bsl + j * 1024 + 512);
        if (t < 127) {
            GLDS16(gB + kof,       &Bs[slot ^ 1][(w8 * 2) * 512]);
            GLDS16(gB + kof + 512, &Bs[slot ^ 1][(w8 * 2 + 1) * 512]);
        }
        __builtin_amdgcn_s_setprio(1);
        #pragma unroll
        for (int i = 0; i < 4; ++i)
            #pragma unroll
            for (int j = 0; j < 2; ++j)
                acc[i][j] = __builtin_amdgcn_mfma_f32_32x32x16_bf16(
                    af1[i], bf1[j], acc[i][j], 0, 0, 0);
        __builtin_amdgcn_s_setprio(0);

        // ---- tile boundary: drain own 4 staging loads, one barrier ----
        if (t < 127) asm volatile("s_waitcnt vmcnt(0)" ::: "memory");
        __builtin_amdgcn_s_barrier();
        __builtin_amdgcn_sched_barrier(0);
    }

    // epilogue: 32x32 C/D layout col = lane&31, row = (reg&3)+8*(reg>>2)+4*lq2
    const int crow_b = m0 + wr * 128 + lq2 * 4;
    const int ccol_b = n0 + wc * 64 + ln31;
    #pragma unroll
    for (int j = 0; j < 2; ++j) {
        const int c = ccol_b + j * 32;
        const float bv = bias[c];
        #pragma unroll
        for (int i = 0; i < 4; ++i) {
            #pragma unroll
            for (int reg = 0; reg < 16; ++reg) {
                const int r = crow_b + i * 32 + (reg & 3) + 8 * (reg >> 2);
                C[(size_t)r * 4096 + c] = acc[i][j][reg] + bv;
            }
        }
    }
}

// ---------------------------------------------------------------------------
extern "C" void kernel_launch(void* const* d_in, const int* in_sizes, int n_in,
                              void* d_out, int out_size, void* d_ws, size_t ws_size,
                              hipStream_t stream) {
    const float* x      = (const float*)d_in[0];   // [4,2048,4096] fp32
    const int*   q      = (const int*)d_in[1];     // [8388608] byte values
    const float* scales = (const float*)d_in[2];   // [262144]
    const float* bias   = (const float*)d_in[3];   // [4096]
    float* out = (float*)d_out;                    // [8192][4096] fp32

    ushort_t* A_pk = (ushort_t*)d_ws;                                     // 64 MB packed x
    ushort_t* B_pk = (ushort_t*)((char*)d_ws + (size_t)64 * 1024 * 1024); // 32 MB packed W

    cast_x_kernel<<<8192, 256, 0, stream>>>(x, A_pk);
    nf4_dequant_t_kernel<<<4096, 256, 0, stream>>>(q, scales, B_pk);
    gemm_nf4_kernel<<<512, 512, 0, stream>>>(A_pk, B_pk, bias, out);
}

// Round 13
// 317.401 us; speedup vs baseline: 1.0335x; 1.0335x over previous
//
#include <hip/hip_runtime.h>
#include <hip/hip_bf16.h>
#include <stdint.h>

typedef __bf16 bf16x8 __attribute__((ext_vector_type(8)));
typedef float f32x16 __attribute__((ext_vector_type(16)));
typedef unsigned short ushort_t;
typedef ushort_t ushort8 __attribute__((ext_vector_type(8)));

#define GLDS16(g, l) __builtin_amdgcn_global_load_lds(                          \
    (const __attribute__((address_space(1))) void*)(g),                         \
    (__attribute__((address_space(3))) void*)(l), 16, 0, 0)

__device__ __constant__ float NF4_LUT_C[16] = {
    -1.0f, -0.6961928009986877f, -0.5250730514526367f, -0.39491748809814453f,
    -0.28444138169288635f, -0.18477343022823334f, -0.09105003625154495f, 0.0f,
    0.07958029955625534f, 0.16093020141124725f, 0.24611230194568634f,
    0.33791524171829224f, 0.44070982933044434f, 0.5626170039176941f,
    0.7229568362236023f, 1.0f};

__device__ inline ushort_t f32_to_bf16(float f) {
    uint32_t u = __builtin_bit_cast(uint32_t, f);
    u += 0x7FFFu + ((u >> 16) & 1u);
    return (ushort_t)(u >> 16);
}

// Packed fragment layout: chunk (b, kb) = 1KB; lane l, elems e 0..7 hold
// value[row = b*32 + (l&31)][k = kb*16 + (l>>5)*8 + e].
// Flat ushort index: (b*256 + kb)*512 + l*8 + e.

// ---------------------------------------------------------------------------
// Kernel 1: cast x (fp32) -> bf16 packed fragments (r9/r10-verified)
// ---------------------------------------------------------------------------
__global__ __launch_bounds__(256) void cast_x_kernel(
    const float* __restrict__ x, ushort_t* __restrict__ A_pk)
{
    __shared__ ushort_t lt[32][130];
    const int t  = threadIdx.x;
    const int mb = blockIdx.x >> 5;
    const int kc = blockIdx.x & 31;

    {
        const int rl = t >> 3;
        const int c0 = (t & 7) * 16;
        const float4* p = reinterpret_cast<const float4*>(
            x + (size_t)(mb * 32 + rl) * 4096 + kc * 128 + c0);
        #pragma unroll
        for (int q = 0; q < 4; ++q) {
            float4 a = p[q];
            lt[rl][c0 + q * 4 + 0] = f32_to_bf16(a.x);
            lt[rl][c0 + q * 4 + 1] = f32_to_bf16(a.y);
            lt[rl][c0 + q * 4 + 2] = f32_to_bf16(a.z);
            lt[rl][c0 + q * 4 + 3] = f32_to_bf16(a.w);
        }
    }
    __syncthreads();

    ushort_t* dst = A_pk + ((size_t)mb * 256 + kc * 8) * 512 + t * 16;
    #pragma unroll
    for (int h = 0; h < 2; ++h) {
        const int c  = 2 * t + h;
        const int kb = c >> 6;
        const int l  = c & 63;
        const int rl = l & 31;
        const int k0 = kb * 16 + (l >> 5) * 8;
        ushort8 v;
        #pragma unroll
        for (int e = 0; e < 8; ++e) v[e] = lt[rl][k0 + e];
        *reinterpret_cast<ushort8*>(dst + h * 8) = v;
    }
}

// ---------------------------------------------------------------------------
// Kernel 2: NF4 dequant -> packed B fragments (r9/r10-verified)
// ---------------------------------------------------------------------------
__global__ __launch_bounds__(256) void nf4_dequant_t_kernel(
    const int* __restrict__ q, const float* __restrict__ scales,
    ushort_t* __restrict__ B_pk)
{
    __shared__ float lut[16];
    __shared__ ushort_t tile[64][65];
    const int t = threadIdx.x;
    if (t < 16) lut[t] = NF4_LUT_C[t];
    __syncthreads();

    const int nt = blockIdx.x & 63;
    const int kt = blockIdx.x >> 6;

    #pragma unroll
    for (int L = t; L < 512; L += 256) {
        const int r  = L >> 3;
        const int qd = L & 7;
        const int k  = kt * 64 + r;
        const int4 e4 = *reinterpret_cast<const int4*>(q + (size_t)k * 2048 + nt * 32 + qd * 4);
        const float s = scales[k * 64 + nt];
        const int nb = qd * 8;
        int bts[4] = {e4.x, e4.y, e4.z, e4.w};
        #pragma unroll
        for (int e = 0; e < 4; ++e) {
            const int byte = bts[e];
            tile[r][nb + e * 2]     = f32_to_bf16(lut[(byte >> 4) & 0xF] * s);
            tile[r][nb + e * 2 + 1] = f32_to_bf16(lut[byte & 0xF] * s);
        }
    }
    __syncthreads();

    #pragma unroll
    for (int h = 0; h < 2; ++h) {
        const int c   = 2 * t + h;
        const int nbl = c >> 8;
        const int kbl = (c >> 6) & 3;
        const int l   = c & 63;
        const int nl  = nbl * 32 + (l & 31);
        const int k0  = kbl * 16 + (l >> 5) * 8;
        ushort8 v;
        #pragma unroll
        for (int e = 0; e < 8; ++e) v[e] = tile[k0 + e][nl];
        ushort_t* dst = B_pk + ((size_t)(nt * 2 + nbl) * 256 + kt * 4 + kbl) * 512 + l * 8;
        *reinterpret_cast<ushort8*>(dst) = v;
    }
}

// ---------------------------------------------------------------------------
// Kernel 3: m201-cadence 4-phase GEMM on packed fragments, CORRECTED stage
// classes. 256x256, BK=64, 2 dbuf x 32KB each side, 8 waves 2Mx4N, 32x32x16.
// Deadness classes (verified vs wave read mapping):
//   A-even {0,1,4,5} dead after q1   -> staged for kt+2 in q2
//   B-even {0,2,4,6} dead after q1   -> staged for kt+2 in q3
//   B-odd  {1,3,5,7} dead after q2   -> staged for kt+2 in q4
//   A-odd  {2,3,6,7} dead after q3   -> staged for kt+1 in q1 (next-parity buf)
// Each stage = 2 x GLDS16 (contiguous 8KB each). vmcnt(6) once per tile at
// q4 = waits the oldest 2 (Ao of kt+1) -> tile kt+1 fully landed. Phase =
// {reads + stage} -> barrier -> lgkmcnt(0) -> setprio(1) 8 MFMA setprio(0)
// -> barrier. The CLOSE barrier (after MFMA) is what orders every wave's
// lgkmcnt(0) before the next phase's stage into the chunks it just read.
// ---------------------------------------------------------------------------
#define SYNC_BEFORE_MFMA() do {                                                 \
    __builtin_amdgcn_sched_barrier(0);                                          \
    __builtin_amdgcn_s_barrier();                                               \
    asm volatile("s_waitcnt lgkmcnt(0)" ::: "memory");                          \
    __builtin_amdgcn_sched_barrier(0);                                          \
} while (0)

#define CLOSE_PHASE() do {                                                      \
    __builtin_amdgcn_sched_barrier(0);                                          \
    __builtin_amdgcn_s_barrier();                                               \
} while (0)

// stage one class (2 blocks b0_, b1_ for this thread) of K-tile kt_ into buf p_
#define STAGE_A(p_, kt_, b0_, b1_) do {                                         \
    GLDS16(aCB + (size_t)(b0_) * 131072 + (kt_) * 2048, &As[p_][(b0_) * 2048 + dOff]); \
    GLDS16(aCB + (size_t)(b1_) * 131072 + (kt_) * 2048, &As[p_][(b1_) * 2048 + dOff]); \
} while (0)
#define STAGE_B(p_, kt_, b0_, b1_) do {                                         \
    GLDS16(bCB + (size_t)(b0_) * 131072 + (kt_) * 2048, &Bs[p_][(b0_) * 2048 + dOff]); \
    GLDS16(bCB + (size_t)(b1_) * 131072 + (kt_) * 2048, &Bs[p_][(b1_) * 2048 + dOff]); \
} while (0)

__global__ __launch_bounds__(512, 2) void gemm_nf4_kernel(
    const ushort_t* __restrict__ A_pk, const ushort_t* __restrict__ B_pk,
    const float* __restrict__ bias, float* __restrict__ C)
{
    __shared__ __align__(16) ushort_t As[2][16384];   // 8 blocks x 4 kb x 512
    __shared__ __align__(16) ushort_t Bs[2][16384];

    const int tid  = threadIdx.x;
    const int lane = tid & 63;
    const int w8   = tid >> 6;
    const int wr   = w8 >> 2;        // 0..1 -> 128-row A strip
    const int wc   = w8 & 3;         // 0..3 -> 64-col B strip
    const int ln31 = lane & 31;
    const int lq2  = lane >> 5;

    // XCD-aware bijective swizzle (512 % 8 == 0)
    const int wg  = blockIdx.x;
    const int swz = (wg & 7) * 64 + (wg >> 3);
    const int m0  = (swz >> 4) * 256;
    const int n0  = (swz & 15) * 256;

    // staging thread decomposition
    const int iA   = tid >> 8;             // 0..1
    const int kbl  = (tid >> 6) & 3;       // local kb
    const int dOff = kbl * 512 + (tid & 63) * 8;
    // class block pairs (h=0, h=1):
    const int Ae0 = iA,         Ae1 = 4 + iA;
    const int Ao0 = 2 + iA,     Ao1 = 6 + iA;
    const int Be0 = 2 * iA,     Be1 = 4 + 2 * iA;
    const int Bo0 = 2 * iA + 1, Bo1 = 5 + 2 * iA;
    // chunk base pointers (add blk*131072 + kt*2048)
    const ushort_t* aCB = A_pk + (size_t)(m0 >> 5) * 131072 + kbl * 512 + (tid & 63) * 8;
    const ushort_t* bCB = B_pk + (size_t)(n0 >> 5) * 131072 + kbl * 512 + (tid & 63) * 8;

    f32x16 acc[4][2];
    #pragma unroll
    for (int i = 0; i < 4; ++i)
        #pragma unroll
        for (int j = 0; j < 2; ++j)
            acc[i][j] = (f32x16){0.f};

    // fragment read bases: A chunk (wr*4+i, kk) -> wr*8192 + i*2048 + kk*512
    const int aOff = wr * 8192 + lane * 8;
    const int bOff = wc * 4096 + lane * 8;

    // prologue: tile0 all 4 classes -> buf0; tile1 Ae,Be,Bo -> buf1
    STAGE_A(0, 0, Ae0, Ae1); STAGE_A(0, 0, Ao0, Ao1);
    STAGE_B(0, 0, Be0, Be1); STAGE_B(0, 0, Bo0, Bo1);
    STAGE_A(1, 1, Ae0, Ae1);
    STAGE_B(1, 1, Be0, Be1); STAGE_B(1, 1, Bo0, Bo1);
    asm volatile("s_waitcnt vmcnt(6)" ::: "memory");   // tile0's 8 landed
    __builtin_amdgcn_s_barrier();
    __builtin_amdgcn_sched_barrier(0);

    for (int kt = 0; kt < 64; ++kt) {
        const int p = kt & 1;
        const ushort_t* Ab = &As[p][aOff];
        const ushort_t* Bb = &Bs[p][bOff];

        bf16x8 af[2][4], bf0[4], bf1[4];

        // ===== q1: 12 reads; stage A-odd(kt+1) -> buf p^1 =====
        #pragma unroll
        for (int i = 0; i < 2; ++i)
            #pragma unroll
            for (int kk = 0; kk < 4; ++kk)
                af[i][kk] = *reinterpret_cast<const bf16x8*>(Ab + i * 2048 + kk * 512);
        #pragma unroll
        for (int kk = 0; kk < 4; ++kk)
            bf0[kk] = *reinterpret_cast<const bf16x8*>(Bb + kk * 512);
        if (kt < 63) STAGE_A(p ^ 1, kt + 1, Ao0, Ao1);
        SYNC_BEFORE_MFMA();
        __builtin_amdgcn_s_setprio(1);
        #pragma unroll
        for (int i = 0; i < 2; ++i)
            #pragma unroll
            for (int kk = 0; kk < 4; ++kk)
                acc[i][0] = __builtin_amdgcn_mfma_f32_32x32x16_bf16(
                    af[i][kk], bf0[kk], acc[i][0], 0, 0, 0);
        __builtin_amdgcn_s_setprio(0);
        CLOSE_PHASE();

        // ===== q2: 4 reads; stage A-even(kt+2) -> buf p =====
        #pragma unroll
        for (int kk = 0; kk < 4; ++kk)
            bf1[kk] = *reinterpret_cast<const bf16x8*>(Bb + 2048 + kk * 512);
        if (kt < 62) STAGE_A(p, kt + 2, Ae0, Ae1);
        SYNC_BEFORE_MFMA();
        __builtin_amdgcn_s_setprio(1);
        #pragma unroll
        for (int i = 0; i < 2; ++i)
            #pragma unroll
            for (int kk = 0; kk < 4; ++kk)
                acc[i][1] = __builtin_amdgcn_mfma_f32_32x32x16_bf16(
                    af[i][kk], bf1[kk], acc[i][1], 0, 0, 0);
        __builtin_amdgcn_s_setprio(0);
        CLOSE_PHASE();

        // ===== q3: 8 reads; stage B-even(kt+2) -> buf p =====
        #pragma unroll
        for (int i = 0; i < 2; ++i)
            #pragma unroll
            for (int kk = 0; kk < 4; ++kk)
                af[i][kk] = *reinterpret_cast<const bf16x8*>(Ab + (2 + i) * 2048 + kk * 512);
        if (kt < 62) STAGE_B(p, kt + 2, Be0, Be1);
        SYNC_BEFORE_MFMA();
        __builtin_amdgcn_s_setprio(1);
        #pragma unroll
        for (int i = 0; i < 2; ++i)
            #pragma unroll
            for (int kk = 0; kk < 4; ++kk)
                acc[2 + i][0] = __builtin_amdgcn_mfma_f32_32x32x16_bf16(
                    af[i][kk], bf0[kk], acc[2 + i][0], 0, 0, 0);
        __builtin_amdgcn_s_setprio(0);
        CLOSE_PHASE();

        // ===== q4: 0 reads; stage B-odd(kt+2) -> buf p; vmcnt =====
        if (kt < 62) {
            STAGE_B(p, kt + 2, Bo0, Bo1);
            asm volatile("s_waitcnt vmcnt(6)" ::: "memory");   // Ao(kt+1) landed
        } else if (kt == 62) {
            asm volatile("s_waitcnt vmcnt(0)" ::: "memory");   // drain Ao(63)
        }
        SYNC_BEFORE_MFMA();
        __builtin_amdgcn_s_setprio(1);
        #pragma unroll
        for (int i = 0; i < 2; ++i)
            #pragma unroll
            for (int kk = 0; kk < 4; ++kk)
                acc[2 + i][1] = __builtin_amdgcn_mfma_f32_32x32x16_bf16(
                    af[i][kk], bf1[kk], acc[2 + i][1], 0, 0, 0);
        __builtin_amdgcn_s_setprio(0);
        CLOSE_PHASE();
    }

    // epilogue: 32x32 C/D layout col = lane&31, row = (reg&3)+8*(reg>>2)+4*lq2
    const int crow_b = m0 + wr * 128 + lq2 * 4;
    const int ccol_b = n0 + wc * 64 + ln31;
    #pragma unroll
    for (int j = 0; j < 2; ++j) {
        const int c = ccol_b + j * 32;
        const float bv = bias[c];
        #pragma unroll
        for (int i = 0; i < 4; ++i) {
            #pragma unroll
            for (int reg = 0; reg < 16; ++reg) {
                const int r = crow_b + i * 32 + (reg & 3) + 8 * (reg >> 2);
                C[(size_t)r * 4096 + c] = acc[i][j][reg] + bv;
            }
        }
    }
}

// ---------------------------------------------------------------------------
extern "C" void kernel_launch(void* const* d_in, const int* in_sizes, int n_in,
                              void* d_out, int out_size, void* d_ws, size_t ws_size,
                              hipStream_t stream) {
    const float* x      = (const float*)d_in[0];   // [4,2048,4096] fp32
    const int*   q      = (const int*)d_in[1];     // [8388608] byte values
    const float* scales = (const float*)d_in[2];   // [262144]
    const float* bias   = (const float*)d_in[3];   // [4096]
    float* out = (float*)d_out;                    // [8192][4096] fp32

    ushort_t* A_pk = (ushort_t*)d_ws;                                     // 64 MB packed x
    ushort_t* B_pk = (ushort_t*)((char*)d_ws + (size_t)64 * 1024 * 1024); // 32 MB packed W

    cast_x_kernel<<<8192, 256, 0, stream>>>(x, A_pk);
    nf4_dequant_t_kernel<<<4096, 256, 0, stream>>>(q, scales, B_pk);
    gemm_nf4_kernel<<<512, 512, 0, stream>>>(A_pk, B_pk, bias, out);
}

// Round 14
// 295.892 us; speedup vs baseline: 1.1087x; 1.0727x over previous
//
#include <hip/hip_runtime.h>
#include <hip/hip_bf16.h>
#include <stdint.h>

typedef __bf16 bf16x8 __attribute__((ext_vector_type(8)));
typedef float f32x16 __attribute__((ext_vector_type(16)));
typedef unsigned short ushort_t;
typedef ushort_t ushort8 __attribute__((ext_vector_type(8)));

#define GLDS16(g, l) __builtin_amdgcn_global_load_lds(                          \
    (const __attribute__((address_space(1))) void*)(g),                         \
    (__attribute__((address_space(3))) void*)(l), 16, 0, 0)

__device__ __constant__ float NF4_LUT_C[16] = {
    -1.0f, -0.6961928009986877f, -0.5250730514526367f, -0.39491748809814453f,
    -0.28444138169288635f, -0.18477343022823334f, -0.09105003625154495f, 0.0f,
    0.07958029955625534f, 0.16093020141124725f, 0.24611230194568634f,
    0.33791524171829224f, 0.44070982933044434f, 0.5626170039176941f,
    0.7229568362236023f, 1.0f};

__device__ inline ushort_t f32_to_bf16(float f) {
    uint32_t u = __builtin_bit_cast(uint32_t, f);
    u += 0x7FFFu + ((u >> 16) & 1u);
    return (ushort_t)(u >> 16);
}

// Packed fragment layout: chunk (b, kb) = 1KB; lane l, elems e 0..7 hold
// value[row = b*32 + (l&31)][k = kb*16 + (l>>5)*8 + e].
// Flat ushort index: (b*256 + kb)*512 + l*8 + e.

// ---------------------------------------------------------------------------
// Kernel 1 (merged prep): blocks 0..8191 cast x->packed A; blocks 8192..12287
// NF4-dequant->packed B. Both memory-bound; one grid lets them overlap on CUs
// instead of serializing at a stream boundary. Branch is block-uniform.
// ---------------------------------------------------------------------------
__global__ __launch_bounds__(256) void prep_kernel(
    const float* __restrict__ x, const int* __restrict__ q,
    const float* __restrict__ scales,
    ushort_t* __restrict__ A_pk, ushort_t* __restrict__ B_pk)
{
    __shared__ ushort_t lt[32][130];
    __shared__ float lut[16];
    __shared__ ushort_t tile[64][65];
    const int t   = threadIdx.x;
    const int bid = blockIdx.x;

    if (bid < 8192) {
        // ---------------- cast part (r9/r10-verified) ----------------
        const int mb = bid >> 5;
        const int kc = bid & 31;
        {
            const int rl = t >> 3;
            const int c0 = (t & 7) * 16;
            const float4* p = reinterpret_cast<const float4*>(
                x + (size_t)(mb * 32 + rl) * 4096 + kc * 128 + c0);
            #pragma unroll
            for (int qq = 0; qq < 4; ++qq) {
                float4 a = p[qq];
                lt[rl][c0 + qq * 4 + 0] = f32_to_bf16(a.x);
                lt[rl][c0 + qq * 4 + 1] = f32_to_bf16(a.y);
                lt[rl][c0 + qq * 4 + 2] = f32_to_bf16(a.z);
                lt[rl][c0 + qq * 4 + 3] = f32_to_bf16(a.w);
            }
        }
        __syncthreads();

        ushort_t* dst = A_pk + ((size_t)mb * 256 + kc * 8) * 512 + t * 16;
        #pragma unroll
        for (int h = 0; h < 2; ++h) {
            const int c  = 2 * t + h;
            const int kb = c >> 6;
            const int l  = c & 63;
            const int rl = l & 31;
            const int k0 = kb * 16 + (l >> 5) * 8;
            ushort8 v;
            #pragma unroll
            for (int e = 0; e < 8; ++e) v[e] = lt[rl][k0 + e];
            *reinterpret_cast<ushort8*>(dst + h * 8) = v;
        }
    } else {
        // ---------------- dequant part (r9/r10-verified) ----------------
        const int bid2 = bid - 8192;
        const int nt = bid2 & 63;
        const int kt = bid2 >> 6;
        if (t < 16) lut[t] = NF4_LUT_C[t];
        __syncthreads();

        #pragma unroll
        for (int L = t; L < 512; L += 256) {
            const int r  = L >> 3;
            const int qd = L & 7;
            const int k  = kt * 64 + r;
            const int4 e4 = *reinterpret_cast<const int4*>(q + (size_t)k * 2048 + nt * 32 + qd * 4);
            const float s = scales[k * 64 + nt];
            const int nb = qd * 8;
            int bts[4] = {e4.x, e4.y, e4.z, e4.w};
            #pragma unroll
            for (int e = 0; e < 4; ++e) {
                const int byte = bts[e];
                tile[r][nb + e * 2]     = f32_to_bf16(lut[(byte >> 4) & 0xF] * s);
                tile[r][nb + e * 2 + 1] = f32_to_bf16(lut[byte & 0xF] * s);
            }
        }
        __syncthreads();

        #pragma unroll
        for (int h = 0; h < 2; ++h) {
            const int c   = 2 * t + h;
            const int nbl = c >> 8;
            const int kbl = (c >> 6) & 3;
            const int l   = c & 63;
            const int nl  = nbl * 32 + (l & 31);
            const int k0  = kbl * 16 + (l >> 5) * 8;
            ushort8 v;
            #pragma unroll
            for (int e = 0; e < 8; ++e) v[e] = tile[k0 + e][nl];
            ushort_t* dst = B_pk + ((size_t)(nt * 2 + nbl) * 256 + kt * 4 + kbl) * 512 + l * 8;
            *reinterpret_cast<ushort8*>(dst) = v;
        }
    }
}

// ---------------------------------------------------------------------------
// Kernel 2: bf16 GEMM, 256x256 tile, BK=32, 8 waves (2M x 4N), 32x32x16 MFMA.
// r10-verified: packed-fragment LDS (zero conflicts, zero VALU addressing,
// coalesced 1KB staging chunks), 4-slot ring, depth-3 prefetch, counted
// vmcnt(8)/4/0, ONE barrier per K32-tile. Best-measured configuration
// (282 us, MfmaUtil 44%, ~1000 TF) across 8 structural variants.
// ---------------------------------------------------------------------------
__global__ __launch_bounds__(512, 2) void gemm_nf4_kernel(
    const ushort_t* __restrict__ A_pk, const ushort_t* __restrict__ B_pk,
    const float* __restrict__ bias, float* __restrict__ C)
{
    __shared__ __align__(16) ushort_t As[4][8192];
    __shared__ __align__(16) ushort_t Bs[4][8192];

    const int tid  = threadIdx.x;
    const int lane = tid & 63;
    const int w8   = tid >> 6;       // 0..7
    const int wr   = w8 >> 2;        // 0..1 -> 128-row A strip
    const int wc   = w8 & 3;         // 0..3 -> 64-col B strip
    const int ln31 = lane & 31;
    const int lq2  = lane >> 5;      // 0..1

    // XCD-aware bijective swizzle (512 % 8 == 0)
    const int wg  = blockIdx.x;
    const int swz = (wg & 7) * 64 + (wg >> 3);
    const int m0  = (swz >> 4) * 256;   // 32 m-tiles
    const int n0  = (swz & 15) * 256;   // 16 n-tiles

    const ushort_t* gA = A_pk + ((size_t)(m0 >> 5) + w8) * (256 * 512) + lane * 8;
    const ushort_t* gB = B_pk + ((size_t)(n0 >> 5) + w8) * (256 * 512) + lane * 8;

    f32x16 acc[4][2];
    #pragma unroll
    for (int i = 0; i < 4; ++i)
        #pragma unroll
        for (int j = 0; j < 2; ++j)
            acc[i][j] = (f32x16){0.f};

    const int aBase = wr * 4096 + lane * 8;
    const int bBase = wc * 2048 + lane * 8;

    // prologue: stage tiles 0,1,2 into slots 0,1,2 (4 loads/wave each)
    #pragma unroll
    for (int tt = 0; tt < 3; ++tt) {
        #pragma unroll
        for (int kb = 0; kb < 2; ++kb) {
            GLDS16(gA + (tt * 2 + kb) * 512, &As[tt][(w8 * 2 + kb) * 512]);
            GLDS16(gB + (tt * 2 + kb) * 512, &Bs[tt][(w8 * 2 + kb) * 512]);
        }
    }
    asm volatile("s_waitcnt vmcnt(8)" ::: "memory");   // tile 0 landed
    __builtin_amdgcn_s_barrier();
    __builtin_amdgcn_sched_barrier(0);

    for (int t = 0; t < 128; ++t) {
        const int slot  = t & 3;
        const int nslot = (t + 3) & 3;
        const ushort_t* Asl = &As[slot][aBase];
        const ushort_t* Bsl = &Bs[slot][bBase];
        const int kof = (t + 3) * 1024;

        // ---- kk = 0: frag reads + stage A chunks of tile t+3 + 8 MFMA ----
        bf16x8 af0[4], bf0[2], af1[4], bf1[2];
        #pragma unroll
        for (int i = 0; i < 4; ++i)
            af0[i] = *reinterpret_cast<const bf16x8*>(Asl + i * 1024);
        #pragma unroll
        for (int j = 0; j < 2; ++j)
            bf0[j] = *reinterpret_cast<const bf16x8*>(Bsl + j * 1024);
        if (t < 125) {
            GLDS16(gA + kof,       &As[nslot][(w8 * 2) * 512]);
            GLDS16(gA + kof + 512, &As[nslot][(w8 * 2 + 1) * 512]);
        }
        __builtin_amdgcn_s_setprio(1);
        #pragma unroll
        for (int i = 0; i < 4; ++i)
            #pragma unroll
            for (int j = 0; j < 2; ++j)
                acc[i][j] = __builtin_amdgcn_mfma_f32_32x32x16_bf16(
                    af0[i], bf0[j], acc[i][j], 0, 0, 0);
        __builtin_amdgcn_s_setprio(0);

        // ---- kk = 1: frag reads + stage B chunks of tile t+3 + 8 MFMA ----
        #pragma unroll
        for (int i = 0; i < 4; ++i)
            af1[i] = *reinterpret_cast<const bf16x8*>(Asl + i * 1024 + 512);
        #pragma unroll
        for (int j = 0; j < 2; ++j)
            bf1[j] = *reinterpret_cast<const bf16x8*>(Bsl + j * 1024 + 512);
        if (t < 125) {
            GLDS16(gB + kof,       &Bs[nslot][(w8 * 2) * 512]);
            GLDS16(gB + kof + 512, &Bs[nslot][(w8 * 2 + 1) * 512]);
        }
        __builtin_amdgcn_s_setprio(1);
        #pragma unroll
        for (int i = 0; i < 4; ++i)
            #pragma unroll
            for (int j = 0; j < 2; ++j)
                acc[i][j] = __builtin_amdgcn_mfma_f32_32x32x16_bf16(
                    af1[i], bf1[j], acc[i][j], 0, 0, 0);
        __builtin_amdgcn_s_setprio(0);

        // ---- tile boundary: own prefetch counted, one barrier ----
        if (t < 125)       asm volatile("s_waitcnt vmcnt(8)" ::: "memory");
        else if (t == 125) asm volatile("s_waitcnt vmcnt(4)" ::: "memory");
        else if (t == 126) asm volatile("s_waitcnt vmcnt(0)" ::: "memory");
        __builtin_amdgcn_s_barrier();
        __builtin_amdgcn_sched_barrier(0);
    }

    // epilogue: 32x32 C/D layout col = lane&31, row = (reg&3)+8*(reg>>2)+4*lq2
    const int crow_b = m0 + wr * 128 + lq2 * 4;
    const int ccol_b = n0 + wc * 64 + ln31;
    #pragma unroll
    for (int j = 0; j < 2; ++j) {
        const int c = ccol_b + j * 32;
        const float bv = bias[c];
        #pragma unroll
        for (int i = 0; i < 4; ++i) {
            #pragma unroll
            for (int reg = 0; reg < 16; ++reg) {
                const int r = crow_b + i * 32 + (reg & 3) + 8 * (reg >> 2);
                C[(size_t)r * 4096 + c] = acc[i][j][reg] + bv;
            }
        }
    }
}

// ---------------------------------------------------------------------------
extern "C" void kernel_launch(void* const* d_in, const int* in_sizes, int n_in,
                              void* d_out, int out_size, void* d_ws, size_t ws_size,
                              hipStream_t stream) {
    const float* x      = (const float*)d_in[0];   // [4,2048,4096] fp32
    const int*   q      = (const int*)d_in[1];     // [8388608] byte values
    const float* scales = (const float*)d_in[2];   // [262144]
    const float* bias   = (const float*)d_in[3];   // [4096]
    float* out = (float*)d_out;                    // [8192][4096] fp32

    ushort_t* A_pk = (ushort_t*)d_ws;                                     // 64 MB packed x
    ushort_t* B_pk = (ushort_t*)((char*)d_ws + (size_t)64 * 1024 * 1024); // 32 MB packed W

    prep_kernel<<<12288, 256, 0, stream>>>(x, q, scales, A_pk, B_pk);
    gemm_nf4_kernel<<<512, 512, 0, stream>>>(A_pk, B_pk, bias, out);
}